// Round 7
// baseline (514.160 us; speedup 1.0000x reference)
//
#include <hip/hip_runtime.h>

typedef _Float16 f16;
typedef _Float16 f16x8 __attribute__((ext_vector_type(8)));
typedef float f32x4 __attribute__((ext_vector_type(4)));

// address_space(1) = global: forces global_load_* (vmcnt-only) instead of
// flat_load_* (which counts in BOTH vmcnt and lgkmcnt and gets drained by
// every lgkm wait — the r2 serializer).
typedef __attribute__((address_space(1))) const f16 gf16;
typedef __attribute__((address_space(1))) const f16x8 gf16x8;

#define N_TOT   8192
#define L_STEPS 32
#define H_DIM   256
#define OUT_DIM 128
#define BN      32
#define NBLK    256
#define THREADS 512

// workspace layout (bytes):
//   Wpack : 262144 f16 = 524288 B @ 0        (W_hh in B-frag order)
//   fcpack:  32768 f16 =  65536 B @ 524288   (fc_w in B-frag order)
//   bsum  :   1024 f32 =   4096 B @ 589824   (b_ih + b_hh)
#define WPACK_OFF  0
#define FCPACK_OFF 524288
#define BSUM_OFF   589824

__global__ __launch_bounds__(256) void prep_kernel(
    const float* __restrict__ W_hh, const float* __restrict__ fc_w,
    const float* __restrict__ b_ih, const float* __restrict__ b_hh,
    f16* __restrict__ Wpack, f16* __restrict__ fcpack, float* __restrict__ bsum)
{
    int p = blockIdx.x * blockDim.x + threadIdx.x;
    if (p < 262144) {
        // Wpack[((kb*64 + T)*64 + lane)*8 + e] = W_hh[g][k]
        // g = 16*T + (lane&15), k = 32*kb + 8*(lane>>4) + e
        int e = p & 7, lane = (p >> 3) & 63, T = (p >> 9) & 63, kb = p >> 15;
        int g = 16 * T + (lane & 15);
        int k = 32 * kb + 8 * (lane >> 4) + e;
        Wpack[p] = (f16)W_hh[g * 256 + k];
    } else if (p < 262144 + 32768) {
        int p2 = p - 262144;
        // fcpack[((kb*8 + ot)*64 + lane)*8 + e] = fc_w[o][k]
        int e = p2 & 7, lane = (p2 >> 3) & 63, ot = (p2 >> 9) & 7, kb = p2 >> 12;
        int o = 16 * ot + (lane & 15);
        int k = 32 * kb + 8 * (lane >> 4) + e;
        fcpack[p2] = (f16)fc_w[o * 256 + k];
    } else if (p < 262144 + 32768 + 1024) {
        int g = p - 262144 - 32768;
        bsum[g] = b_ih[g] + b_hh[g];
    }
}

__device__ __forceinline__ float sigmoid_(float x) {
    return 1.0f / (1.0f + __expf(-x));
}
__device__ __forceinline__ float tanh_(float x) {
    float t = __expf(-2.0f * x);
    return (1.0f - t) / (1.0f + t);
}

// LDS-only barrier: ds ops complete (lgkmcnt), but global weight loads and
// output stores stay IN FLIGHT across it.
__device__ __forceinline__ void lds_barrier() {
    asm volatile("s_waitcnt lgkmcnt(0)" ::: "memory");
    __builtin_amdgcn_s_barrier();
    asm volatile("" ::: "memory");
}

// 256 blocks x 512 threads (8 waves, 2 waves/SIMD, 1 block/CU).
// Per step (ONE barrier): [x + consts from LDS -> x-proj] [8 fused phases:
// ds_read a0/a1 -> 16 gate MFMA + 2 fc MFMA (fc for step l-1 reuses the
// same A-frags since hp[buf]==hs[l-1]) + depth-3 weight refill]
// [facc -> obuf[ob]] [elementwise -> hp[buf^1]] [lds_barrier]
// [cooperative whole-line global write of out[:, l-1, :] from obuf[ob]].
//
// r4 lesson: direct per-lane out stores -> partial-line RMW at TCC (823 MB
// fetch). obuf staging makes whole-line writes; never remove it.
// r5 lesson: exceeding the 256-reg unified budget at 2 waves/SIMD ->
// scratch spill (FETCH 198/WRITE 404 MB). r6 lesson: weight pipe depth-2
// is NOT enough cover: per phase the CU's 8 waves issue 64 KB of refills
// (1024 cyc L1 drain) but 2 phases of MFMA are only ~700 cyc -> per-phase
// wbuf stall. This rev: depth-3 wbuf (r3 schedule) + fc fusion, paid for
// by moving the x-proj constants (24 regs) into LDS.
//
// Weight pipe: 3 slots, s = p%3; refill just-consumed slot for its next
// consumer: p<=4 -> phase p+3 this step; p=5,6,7 -> NEXT step's phases
// 2,0,1 (loads fly across the elementwise window + lgkm-only barrier).
// Per-wave kb stagger OFF=(kb0+wave)&7: waves sweep kb in different order
// (commutative), spreading L2 regions and hp LDS slices per phase.
// fcw loaded PRE-ROTATED by OFF so the phase loop indexes it with
// compile-time p (runtime-indexed reg arrays go to scratch).
__global__ __launch_bounds__(THREADS, 2) void lstm_kernel(
    const float* __restrict__ x, const float* __restrict__ W_ih,
    const f16* __restrict__ Wpack, const float* __restrict__ bsum,
    const f16* __restrict__ fcpack, const float* __restrict__ fc_b,
    float* __restrict__ out)
{
    __shared__ __align__(16) f16 hp[2][8192];             // h A-frag order, dbuf (32 KB)
    __shared__ __align__(16) float obuf[2][BN * OUT_DIM]; // fc staging, dbuf (32 KB)
    __shared__ __align__(16) float2 xbuf[BN * 34];        // x slice, padded rows (8.5 KB)
    __shared__ __align__(16) float2 cw2[1024];            // (W_ih[g][0], W_ih[g][1]) (8 KB)
    __shared__ float cwb[1024];                           // b_ih+b_hh (4 KB)

    const int tid  = threadIdx.x;
    const int wave = tid >> 6;
    const int lane = tid & 63;
    const int l15  = lane & 15;
    const int lq   = lane >> 4;
    const int n0   = blockIdx.x * BN;
    const int kb0  = (blockIdx.x >> 3) & 7;   // L2 de-hotspot rotation
    const int OFF  = (kb0 + wave) & 7;        // + per-wave stagger

    // ---- resident fc B-frags, pre-rotated: fcw[p] = frag of kb=(p+OFF)&7 ----
    f16x8 fcw[8];
#pragma unroll
    for (int p = 0; p < 8; ++p) {
        int kb = (p + OFF) & 7;
        fcw[p] = *(const f16x8*)&fcpack[((kb * 8 + wave) * 64 + lane) * 8];
    }

    // h(t=0) = 0
    for (int i = tid; i < 8192; i += THREADS) hp[0][i] = (f16)0.0f;

    // ---- stage the block's x slice into LDS (8 KB, read once from HBM) ----
    {
        const int row = tid >> 4, part = tid & 15;
        f32x4 v = *(const f32x4*)&x[(n0 + row) * (L_STEPS * 2) + part * 4];
        xbuf[row * 34 + 2 * part + 0] = make_float2(v[0], v[1]);
        xbuf[row * 34 + 2 * part + 1] = make_float2(v[2], v[3]);
    }
    // ---- stage x-proj constants into LDS (frees 24 persistent VGPRs) ----
    for (int g = tid; g < 1024; g += THREADS) {
        cw2[g] = make_float2(W_ih[2 * g], W_ih[2 * g + 1]);
        cwb[g] = bsum[g];
    }

    const float fcbv = fc_b[16 * wave + l15];
    const int   ocol = 16 * wave + l15;

    float c[2][2][4];
#pragma unroll
    for (int ti = 0; ti < 2; ++ti)
#pragma unroll
        for (int mt = 0; mt < 2; ++mt)
#pragma unroll
            for (int r = 0; r < 4; ++r) c[ti][mt][r] = 0.0f;

    // weight stream base
    unsigned long long wb_u =
        (unsigned long long)(uintptr_t)(Wpack + wave * 512 + lane * 8);
    // const-read index base (opaque'd per step to stop LICM re-hoisting the
    // loop-invariant LDS reads back into 24 persistent registers)
    int gbase = 16 * wave + l15;

    // prologue: slots 0,1,2 <- OFF, OFF+1, OFF+2 (consumed at p=0,1,2)
    f16x8 wbuf[3][2][4];  // [slot][ti][q] — slot index always compile-time
    {
        gf16* wb = (gf16*)(uintptr_t)wb_u;
#pragma unroll
        for (int s = 0; s < 3; ++s) {
            int kb = (OFF + s) & 7;
#pragma unroll
            for (int ti = 0; ti < 2; ++ti)
#pragma unroll
                for (int q = 0; q < 4; ++q)
                    wbuf[s][ti][q] =
                        *(const gf16x8*)&wb[kb * 32768 + q * 8192 + ti * 4096];
        }
    }

    __syncthreads();  // one-time full sync (h init + xbuf + consts visible)

    int buf = 0;
#pragma unroll 1
    for (int l = 0; l < L_STEPS; ++l) {
        const int ob = l & 1;
        // Defeat LICM on the l-invariant weight/const loads (r0 spill bug).
        asm volatile("" : "+v"(wb_u));
        gf16* wb = (gf16*)(uintptr_t)wb_u;
        int gb = gbase;
        asm volatile("" : "+v"(gb));

        // ---- x + consts from LDS (short-lived temps) ----
        float2 xv[2][4];
#pragma unroll
        for (int mt = 0; mt < 2; ++mt)
#pragma unroll
            for (int r = 0; r < 4; ++r)
                xv[mt][r] = xbuf[(16 * mt + 4 * lq + r) * 34 + l];

        // ---- accumulator init = x-projection (fp32 exact) ----
        f32x4 acc[2][2][4];  // [ti][mt][q]
#pragma unroll
        for (int ti = 0; ti < 2; ++ti)
#pragma unroll
            for (int q = 0; q < 4; ++q) {
                int g = 256 * q + 128 * ti + gb;   // = 256q + 16(wave+8ti) + l15
                float2 w01 = cw2[g];
                float  bs  = cwb[g];
#pragma unroll
                for (int mt = 0; mt < 2; ++mt)
#pragma unroll
                    for (int r = 0; r < 4; ++r)
                        acc[ti][mt][q][r] = bs + xv[mt][r].x * w01.x
                                               + xv[mt][r].y * w01.y;
            }

        // fc accumulator for output l-1 (at l=0: consumes h0=0, discarded)
        f32x4 facc0 = {fcbv, fcbv, fcbv, fcbv};
        f32x4 facc1 = facc0;

        // ---- 8 fused phases: gates(l) + fc(l-1) + depth-3 weight refill ----
#pragma unroll
        for (int p = 0; p < 8; ++p) {
            const int s    = p % 3;            // slot (compile-time)
            const int kb_c = (p + OFF) & 7;    // kb consumed (addr math only)

            f16x8 a0 = *(const f16x8*)&hp[buf][((kb_c * 2 + 0) * 64 + lane) * 8];
            f16x8 a1 = *(const f16x8*)&hp[buf][((kb_c * 2 + 1) * 64 + lane) * 8];
#pragma unroll
            for (int ti = 0; ti < 2; ++ti)
#pragma unroll
                for (int q = 0; q < 4; ++q) {
                    acc[ti][0][q] = __builtin_amdgcn_mfma_f32_16x16x32_f16(
                        a0, wbuf[s][ti][q], acc[ti][0][q], 0, 0, 0);
                    acc[ti][1][q] = __builtin_amdgcn_mfma_f32_16x16x32_f16(
                        a1, wbuf[s][ti][q], acc[ti][1][q], 0, 0, 0);
                }
            // fused fc (same A-frags, pre-rotated B): out(l-1) accumulation
            facc0 = __builtin_amdgcn_mfma_f32_16x16x32_f16(a0, fcw[p], facc0, 0, 0, 0);
            facc1 = __builtin_amdgcn_mfma_f32_16x16x32_f16(a1, fcw[p], facc1, 0, 0, 0);

            // refill the just-consumed slot for its NEXT consumer:
            // p<=4 -> phase p+3 this step; p=5,6,7 -> next step's phase 2,0,1
            const int pn   = (p <= 4) ? (p + 3) : (p == 5 ? 2 : (p == 6 ? 0 : 1));
            const int kb_n = (pn + OFF) & 7;
#pragma unroll
            for (int ti = 0; ti < 2; ++ti)
#pragma unroll
                for (int q = 0; q < 4; ++q)
                    wbuf[s][ti][q] =
                        *(const gf16x8*)&wb[kb_n * 32768 + q * 8192 + ti * 4096];
        }

        // ---- stage fc(l-1) into LDS (whole-line global writes need this) ----
#pragma unroll
        for (int r = 0; r < 4; ++r) {
            obuf[ob][(4 * lq + r) * OUT_DIM + ocol]        = facc0[r];
            obuf[ob][(16 + 4 * lq + r) * OUT_DIM + ocol]   = facc1[r];
        }

        // ---- elementwise LSTM update (all 4 gates in-register per lane) ----
#pragma unroll
        for (int ti = 0; ti < 2; ++ti) {
            int j   = 16 * (wave + 8 * ti) + l15;
            int kbj = j >> 5, qk = (j >> 3) & 3, e = j & 7;
#pragma unroll
            for (int mt = 0; mt < 2; ++mt)
#pragma unroll
                for (int r = 0; r < 4; ++r) {
                    float gi = acc[ti][mt][0][r];
                    float gf = acc[ti][mt][1][r];
                    float gg = acc[ti][mt][2][r];
                    float go = acc[ti][mt][3][r];
                    float cn = sigmoid_(gf) * c[ti][mt][r] + sigmoid_(gi) * tanh_(gg);
                    c[ti][mt][r] = cn;
                    float hv = sigmoid_(go) * tanh_(cn);
                    int laneA = (4 * lq + r) | (qk << 4);
                    hp[buf ^ 1][((kbj * 2 + mt) * 64 + laneA) * 8 + e] = (f16)hv;
                }
        }
        lds_barrier();  // h_new + obuf[ob] visible; weight prefetch in flight

        // ---- cooperative, line-contiguous global write of out[:, l-1, :] ----
        if (l > 0) {
            const int row = tid >> 4;
            const int gl  = ((n0 + row) * L_STEPS + (l - 1)) * OUT_DIM;
#pragma unroll
            for (int half = 0; half < 2; ++half) {
                int col = (tid & 15) * 4 + half * 64;
                f32x4 v = *(const f32x4*)&obuf[ob][row * OUT_DIM + col];
                *(f32x4*)&out[gl + col] = v;
            }
        }

        buf ^= 1;
    }

    // ---- epilogue: out[:, 31, :] = fc(hs[31]) via obuf[0] ----
    {
        f32x4 e0 = {fcbv, fcbv, fcbv, fcbv};
        f32x4 e1 = e0;
#pragma unroll
        for (int p = 0; p < 8; ++p) {
            const int kb_c = (p + OFF) & 7;
            f16x8 a0 = *(const f16x8*)&hp[buf][((kb_c * 2 + 0) * 64 + lane) * 8];
            f16x8 a1 = *(const f16x8*)&hp[buf][((kb_c * 2 + 1) * 64 + lane) * 8];
            e0 = __builtin_amdgcn_mfma_f32_16x16x32_f16(a0, fcw[p], e0, 0, 0, 0);
            e1 = __builtin_amdgcn_mfma_f32_16x16x32_f16(a1, fcw[p], e1, 0, 0, 0);
        }
#pragma unroll
        for (int r = 0; r < 4; ++r) {
            obuf[0][(4 * lq + r) * OUT_DIM + ocol]        = e0[r];
            obuf[0][(16 + 4 * lq + r) * OUT_DIM + ocol]   = e1[r];
        }
        __syncthreads();
        const int row = tid >> 4;
        const int gl  = ((n0 + row) * L_STEPS + 31) * OUT_DIM;
#pragma unroll
        for (int half = 0; half < 2; ++half) {
            int col = (tid & 15) * 4 + half * 64;
            f32x4 v = *(const f32x4*)&obuf[0][row * OUT_DIM + col];
            *(f32x4*)&out[gl + col] = v;
        }
    }
}

extern "C" void kernel_launch(void* const* d_in, const int* in_sizes, int n_in,
                              void* d_out, int out_size, void* d_ws, size_t ws_size,
                              hipStream_t stream) {
    const float* x    = (const float*)d_in[0];
    const float* W_ih = (const float*)d_in[1];
    const float* W_hh = (const float*)d_in[2];
    const float* b_ih = (const float*)d_in[3];
    const float* b_hh = (const float*)d_in[4];
    const float* fc_w = (const float*)d_in[5];
    const float* fc_b = (const float*)d_in[6];
    float* out = (float*)d_out;

    char* ws = (char*)d_ws;
    f16*   Wpack  = (f16*)(ws + WPACK_OFF);
    f16*   fcpack = (f16*)(ws + FCPACK_OFF);
    float* bsum   = (float*)(ws + BSUM_OFF);

    const int prep_elems = 262144 + 32768 + 1024;
    prep_kernel<<<(prep_elems + 255) / 256, 256, 0, stream>>>(
        W_hh, fc_w, b_ih, b_hh, Wpack, fcpack, bsum);

    lstm_kernel<<<NBLK, THREADS, 0, stream>>>(
        x, W_ih, Wpack, bsum, fcpack, fc_b, out);
}

// Round 8
// 504.915 us; speedup vs baseline: 1.0183x; 1.0183x over previous
//
#include <hip/hip_runtime.h>

typedef _Float16 f16;
typedef _Float16 f16x8 __attribute__((ext_vector_type(8)));
typedef float f32x4 __attribute__((ext_vector_type(4)));

// address_space(1) = global: forces global_load_* (vmcnt-only) instead of
// flat_load_* (which counts in BOTH vmcnt and lgkmcnt and gets drained by
// every lgkm wait — the r2 serializer).
typedef __attribute__((address_space(1))) const f16 gf16;
typedef __attribute__((address_space(1))) const f16x8 gf16x8;
typedef __attribute__((address_space(1))) const char gchar;

#define N_TOT   8192
#define L_STEPS 32
#define H_DIM   256
#define OUT_DIM 128
#define BN      32
#define NBLK    256
#define THREADS 512

// workspace layout (bytes):
//   Wpack : 262144 f16 = 524288 B @ 0        (W_hh in B-frag order)
//   fcpack:  32768 f16 =  65536 B @ 524288   (fc_w in B-frag order)
//   bsum  :   1024 f32 =   4096 B @ 589824   (b_ih + b_hh)
#define WPACK_OFF  0
#define FCPACK_OFF 524288
#define BSUM_OFF   589824

__global__ __launch_bounds__(256) void prep_kernel(
    const float* __restrict__ W_hh, const float* __restrict__ fc_w,
    const float* __restrict__ b_ih, const float* __restrict__ b_hh,
    f16* __restrict__ Wpack, f16* __restrict__ fcpack, float* __restrict__ bsum)
{
    int p = blockIdx.x * blockDim.x + threadIdx.x;
    if (p < 262144) {
        // Wpack[((kb*64 + T)*64 + lane)*8 + e] = W_hh[g][k]
        // g = 16*T + (lane&15), k = 32*kb + 8*(lane>>4) + e
        int e = p & 7, lane = (p >> 3) & 63, T = (p >> 9) & 63, kb = p >> 15;
        int g = 16 * T + (lane & 15);
        int k = 32 * kb + 8 * (lane >> 4) + e;
        Wpack[p] = (f16)W_hh[g * 256 + k];
    } else if (p < 262144 + 32768) {
        int p2 = p - 262144;
        // fcpack[((kb*8 + ot)*64 + lane)*8 + e] = fc_w[o][k]
        int e = p2 & 7, lane = (p2 >> 3) & 63, ot = (p2 >> 9) & 7, kb = p2 >> 12;
        int o = 16 * ot + (lane & 15);
        int k = 32 * kb + 8 * (lane >> 4) + e;
        fcpack[p2] = (f16)fc_w[o * 256 + k];
    } else if (p < 262144 + 32768 + 1024) {
        int g = p - 262144 - 32768;
        bsum[g] = b_ih[g] + b_hh[g];
    }
}

__device__ __forceinline__ float sigmoid_(float x) {
    return 1.0f / (1.0f + __expf(-x));
}
__device__ __forceinline__ float tanh_(float x) {
    float t = __expf(-2.0f * x);
    return (1.0f - t) / (1.0f + t);
}

// LDS-only barrier: ds ops complete (lgkmcnt), but global weight loads and
// output stores stay IN FLIGHT across it.
__device__ __forceinline__ void lds_barrier() {
    asm volatile("s_waitcnt lgkmcnt(0)" ::: "memory");
    __builtin_amdgcn_s_barrier();
    asm volatile("" ::: "memory");
}

// 256 blocks x 512 threads (8 waves, 2 waves/SIMD, 1 block/CU).
// Per step (ONE barrier):
//   [x-proj from xbuf] [8 gate phases: ds_read a0/a1 -> 16 MFMA + depth-3
//   weight refill via SADDR loads] [elementwise -> hp[buf^1]] [lds_barrier]
//   [cooperative whole-line store of out[:, l-1, :] from obuf[(l-1)&1]]
//   [fc(hs[l]): 16 ds_read + 16 MFMA -> obuf[l&1]]
// The fc stage is UNFUSED (r5/r6/r7 lesson: fusing fc into the gate phases
// exceeds the 256-reg unified budget -> scratch spill, FETCH 62-198 MB).
// Its obuf write is deferred one step (double-buffered obuf), so barrier B
// is gone: every producer/consumer pair is separated by the next step's
// lgkmcnt(0)+s_barrier.
// r4 lesson: direct per-lane out stores -> partial-line RMW at TCC (823 MB
// fetch). obuf staging makes whole-line writes; never remove it.
//
// Weight stream addressing: base pointer stays UNIFORM (SGPR pair; it is
// never touched by the anti-LICM asm), per-lane part lives in 8 persistent
// 32-bit byte offsets voffB[ti][q]. uniform-base + divergent-32b-offset
// makes clang emit global_load_dwordx4_saddr: kb_n*65536 is SALU, ZERO
// per-load VALU (r3 spent ~60 VALU/phase on 64-bit vector address adds —
// the bulk of its 60% VALUBusy). LICM of the l-invariant loads (the r0
// spill bug) is defeated by opaque-ing voffB once per step.
// Weight pipe: 3 slots, s = p%3 (r6 lesson: depth-2 is not enough cover);
// refill just-consumed slot for its next consumer: p<=4 -> phase p+3 this
// step; p=5,6,7 -> NEXT step's phases 2,0,1 (those loads fly across the
// elementwise window, the barrier, the coop store and the fc stage).
// kb sweep rotated per block (kb0) to de-hotspot the per-XCD L2.
__global__ __launch_bounds__(THREADS, 2) void lstm_kernel(
    const float* __restrict__ x, const float* __restrict__ W_ih,
    const f16* __restrict__ Wpack, const float* __restrict__ bsum,
    const f16* __restrict__ fcpack, const float* __restrict__ fc_b,
    float* __restrict__ out)
{
    __shared__ __align__(16) f16 hp[2][8192];             // h A-frag order, dbuf (32 KB)
    __shared__ __align__(16) float obuf[2][BN * OUT_DIM]; // fc staging, dbuf (32 KB)
    __shared__ __align__(16) float2 xbuf[BN * 34];        // x slice, padded rows (8.5 KB)

    const int tid  = threadIdx.x;
    const int wave = tid >> 6;
    const int lane = tid & 63;
    const int l15  = lane & 15;
    const int lq   = lane >> 4;
    const int n0   = blockIdx.x * BN;
    const int kb0  = (blockIdx.x >> 3) & 7;   // L2 de-hotspot rotation

    // ---- resident fc B-frags, NATURAL order (fc stage is unfused) ----
    f16x8 fcw[8];
#pragma unroll
    for (int kb = 0; kb < 8; ++kb)
        fcw[kb] = *(const f16x8*)&fcpack[((kb * 8 + wave) * 64 + lane) * 8];

    // h(t=0) = 0
    for (int i = tid; i < 8192; i += THREADS) hp[0][i] = (f16)0.0f;

    // ---- stage the block's x slice into LDS (8 KB, read once from HBM) ----
    {
        const int row = tid >> 4, part = tid & 15;
        f32x4 v = *(const f32x4*)&x[(n0 + row) * (L_STEPS * 2) + part * 4];
        xbuf[row * 34 + 2 * part + 0] = make_float2(v[0], v[1]);
        xbuf[row * 34 + 2 * part + 1] = make_float2(v[2], v[3]);
    }

    // per-lane x-projection constants: g = 256*q + 16*(wave + 8*ti) + l15
    float wih0[2][4], wih1[2][4], bsv[2][4];
#pragma unroll
    for (int ti = 0; ti < 2; ++ti)
#pragma unroll
        for (int q = 0; q < 4; ++q) {
            int g = 256 * q + 16 * (wave + 8 * ti) + l15;
            wih0[ti][q] = W_ih[g * 2 + 0];
            wih1[ti][q] = W_ih[g * 2 + 1];
            bsv[ti][q]  = bsum[g];
        }
    const float fcbv = fc_b[16 * wave + l15];
    const int   ocol = 16 * wave + l15;

    float c[2][2][4];
#pragma unroll
    for (int ti = 0; ti < 2; ++ti)
#pragma unroll
        for (int mt = 0; mt < 2; ++mt)
#pragma unroll
            for (int r = 0; r < 4; ++r) c[ti][mt][r] = 0.0f;

    // ---- weight stream: UNIFORM base (SGPR) + divergent 32-bit offsets ----
    gchar* wb0 = (gchar*)(uintptr_t)Wpack;   // never opaque'd -> stays SGPR
    unsigned voffB[2][4];                    // bytes within a kb tile
#pragma unroll
    for (int ti = 0; ti < 2; ++ti)
#pragma unroll
        for (int q = 0; q < 4; ++q)
            voffB[ti][q] = 2u * (q * 8192 + ti * 4096 + wave * 512 + lane * 8);

    // prologue: slots 0,1,2 <- kb0, kb0+1, kb0+2 (consumed at p=0,1,2)
    f16x8 wbuf[3][2][4];  // [slot][ti][q] — slot index always compile-time
#pragma unroll
    for (int s = 0; s < 3; ++s) {
        gchar* base = wb0 + (((kb0 + s) & 7) * 65536);
#pragma unroll
        for (int ti = 0; ti < 2; ++ti)
#pragma unroll
            for (int q = 0; q < 4; ++q)
                wbuf[s][ti][q] = *(const gf16x8*)(base + voffB[ti][q]);
    }

    __syncthreads();  // one-time full sync (h init + xbuf visible)

    int buf = 0;
#pragma unroll 1
    for (int l = 0; l < L_STEPS; ++l) {
        // Defeat LICM on the l-invariant weight loads (the r0 spill bug):
        // opaque the divergent offsets, NOT the base (base must stay SGPR).
#pragma unroll
        for (int ti = 0; ti < 2; ++ti)
#pragma unroll
            for (int q = 0; q < 4; ++q)
                asm volatile("" : "+v"(voffB[ti][q]));

        // ---- x from LDS (short-lived temps) ----
        float2 xv[2][4];
#pragma unroll
        for (int mt = 0; mt < 2; ++mt)
#pragma unroll
            for (int r = 0; r < 4; ++r)
                xv[mt][r] = xbuf[(16 * mt + 4 * lq + r) * 34 + l];

        // ---- accumulator init = x-projection (fp32 exact) ----
        f32x4 acc[2][2][4];  // [ti][mt][q]
#pragma unroll
        for (int mt = 0; mt < 2; ++mt)
#pragma unroll
            for (int r = 0; r < 4; ++r) {
#pragma unroll
                for (int ti = 0; ti < 2; ++ti)
#pragma unroll
                    for (int q = 0; q < 4; ++q)
                        acc[ti][mt][q][r] = bsv[ti][q] + xv[mt][r].x * wih0[ti][q]
                                                       + xv[mt][r].y * wih1[ti][q];
            }

        // ---- 8 gate phases: MFMA + depth-3 SADDR weight refill ----
#pragma unroll
        for (int p = 0; p < 8; ++p) {
            const int s    = p % 3;            // slot (compile-time)
            const int kb_c = (p + kb0) & 7;    // kb consumed

            f16x8 a0 = *(const f16x8*)&hp[buf][((kb_c * 2 + 0) * 64 + lane) * 8];
            f16x8 a1 = *(const f16x8*)&hp[buf][((kb_c * 2 + 1) * 64 + lane) * 8];
#pragma unroll
            for (int ti = 0; ti < 2; ++ti)
#pragma unroll
                for (int q = 0; q < 4; ++q) {
                    acc[ti][0][q] = __builtin_amdgcn_mfma_f32_16x16x32_f16(
                        a0, wbuf[s][ti][q], acc[ti][0][q], 0, 0, 0);
                    acc[ti][1][q] = __builtin_amdgcn_mfma_f32_16x16x32_f16(
                        a1, wbuf[s][ti][q], acc[ti][1][q], 0, 0, 0);
                }

            // refill the just-consumed slot for its NEXT consumer:
            // p<=4 -> phase p+3 this step; p=5,6,7 -> next step's phase 2,0,1
            const int pn   = (p <= 4) ? (p + 3) : (p == 5 ? 2 : (p == 6 ? 0 : 1));
            gchar* base = wb0 + (((pn + kb0) & 7) * 65536);  // SALU only
#pragma unroll
            for (int ti = 0; ti < 2; ++ti)
#pragma unroll
                for (int q = 0; q < 4; ++q)
                    wbuf[s][ti][q] = *(const gf16x8*)(base + voffB[ti][q]);
        }

        // ---- elementwise LSTM update (all 4 gates in-register per lane) ----
#pragma unroll
        for (int ti = 0; ti < 2; ++ti) {
            int j   = 16 * (wave + 8 * ti) + l15;
            int kbj = j >> 5, qk = (j >> 3) & 3, e = j & 7;
#pragma unroll
            for (int mt = 0; mt < 2; ++mt)
#pragma unroll
                for (int r = 0; r < 4; ++r) {
                    float gi = acc[ti][mt][0][r];
                    float gf = acc[ti][mt][1][r];
                    float gg = acc[ti][mt][2][r];
                    float go = acc[ti][mt][3][r];
                    float cn = sigmoid_(gf) * c[ti][mt][r] + sigmoid_(gi) * tanh_(gg);
                    c[ti][mt][r] = cn;
                    float hv = sigmoid_(go) * tanh_(cn);
                    int laneA = (4 * lq + r) | (qk << 4);
                    hp[buf ^ 1][((kbj * 2 + mt) * 64 + laneA) * 8 + e] = (f16)hv;
                }
        }
        lds_barrier();  // h_new + obuf[(l-1)&1] visible; prefetch in flight

        // ---- cooperative whole-line store of out[:, l-1, :] (deferred) ----
        if (l > 0) {
            const int row = tid >> 4;
            const int gl  = ((n0 + row) * L_STEPS + (l - 1)) * OUT_DIM;
#pragma unroll
            for (int half = 0; half < 2; ++half) {
                int col = (tid & 15) * 4 + half * 64;
                f32x4 v = *(const f32x4*)&obuf[(l - 1) & 1][row * OUT_DIM + col];
                *(f32x4*)&out[gl + col] = v;
            }
        }

        // ---- fc(hs[l]) -> obuf[l&1] (read by NEXT step's coop store) ----
        {
            f32x4 facc0 = {fcbv, fcbv, fcbv, fcbv};
            f32x4 facc1 = facc0;
#pragma unroll
            for (int kb = 0; kb < 8; ++kb) {  // compile-time ds offsets
                f16x8 a0 = *(const f16x8*)&hp[buf ^ 1][((kb * 2 + 0) * 64 + lane) * 8];
                f16x8 a1 = *(const f16x8*)&hp[buf ^ 1][((kb * 2 + 1) * 64 + lane) * 8];
                facc0 = __builtin_amdgcn_mfma_f32_16x16x32_f16(a0, fcw[kb], facc0, 0, 0, 0);
                facc1 = __builtin_amdgcn_mfma_f32_16x16x32_f16(a1, fcw[kb], facc1, 0, 0, 0);
            }
#pragma unroll
            for (int r = 0; r < 4; ++r) {
                obuf[l & 1][(4 * lq + r) * OUT_DIM + ocol]      = facc0[r];
                obuf[l & 1][(16 + 4 * lq + r) * OUT_DIM + ocol] = facc1[r];
            }
        }

        buf ^= 1;
    }

    // ---- epilogue: store out[:, 31, :] from obuf[31&1 = 1] ----
    __syncthreads();
    {
        const int row = tid >> 4;
        const int gl  = ((n0 + row) * L_STEPS + 31) * OUT_DIM;
#pragma unroll
        for (int half = 0; half < 2; ++half) {
            int col = (tid & 15) * 4 + half * 64;
            f32x4 v = *(const f32x4*)&obuf[1][row * OUT_DIM + col];
            *(f32x4*)&out[gl + col] = v;
        }
    }
}

extern "C" void kernel_launch(void* const* d_in, const int* in_sizes, int n_in,
                              void* d_out, int out_size, void* d_ws, size_t ws_size,
                              hipStream_t stream) {
    const float* x    = (const float*)d_in[0];
    const float* W_ih = (const float*)d_in[1];
    const float* W_hh = (const float*)d_in[2];
    const float* b_ih = (const float*)d_in[3];
    const float* b_hh = (const float*)d_in[4];
    const float* fc_w = (const float*)d_in[5];
    const float* fc_b = (const float*)d_in[6];
    float* out = (float*)d_out;

    char* ws = (char*)d_ws;
    f16*   Wpack  = (f16*)(ws + WPACK_OFF);
    f16*   fcpack = (f16*)(ws + FCPACK_OFF);
    float* bsum   = (float*)(ws + BSUM_OFF);

    const int prep_elems = 262144 + 32768 + 1024;
    prep_kernel<<<(prep_elems + 255) / 256, 256, 0, stream>>>(
        W_hh, fc_w, b_ih, b_hh, Wpack, fcpack, bsum);

    lstm_kernel<<<NBLK, THREADS, 0, stream>>>(
        x, W_ih, Wpack, bsum, fcpack, fc_b, out);
}